// Round 13
// baseline (220.719 us; speedup 1.0000x reference)
//
#include <hip/hip_runtime.h>
#include <stdint.h>

typedef _Float16 f16;
typedef __attribute__((ext_vector_type(8))) _Float16 f16x8;
typedef __attribute__((ext_vector_type(4))) float f32x4;

#define BATCH 8192
#define INF   1024
#define OUTF  1024
#define KTOT  9216
#define NT    72    /* K-tiles of 64 per split (4608/64) */
#define NKT   144   /* total K-tiles (both splits) */
#define CONV_BLOCKS 4608   /* 1024*1152/256 */

// ---------------------------------------------------------------------------
__device__ __forceinline__ void gload16(const void* g, void* l) {
  __builtin_amdgcn_global_load_lds(
      (const __attribute__((address_space(1))) uint32_t*)g,
      (__attribute__((address_space(3))) uint32_t*)l, 16, 0, 0);
}

// ---------------------------------------------------------------------------
// Fused prep: blocks [0, CONV_BLOCKS) convert W -> f16 FRAGMENT-ORDER layout
//   Wc[(tn*144+kt)*16384 + wcn*4096 + (s*4+n)*512 + (lb*16+la)*8 .. +8)
//   = W row (tn*256+wcn*64+n*16+la), k (kt*64 + (s*4+lb)*8 .. +8)
// so each B-frag register load in the GEMM is one coalesced dwordx4.
// Remaining blocks build A (silu | spline basis), unchanged (proven).
// ---------------------------------------------------------------------------
__global__ __launch_bounds__(256) void fused_prep_kernel(
    const float* __restrict__ bw, const float* __restrict__ sw,
    const float* __restrict__ x, const float* __restrict__ grid,
    f16* __restrict__ Wc, f16* __restrict__ Abuf)
{
  int blk = blockIdx.x;
  if (blk < CONV_BLOCKS) {
    int idx = blk * 256 + threadIdx.x;   // [0, 1024*1152)
    int o = idx / 1152;
    int r = idx - o * 1152;
    int k8 = r * 8;
    const float* src = (k8 < INF) ? (bw + (size_t)o * INF + k8)
                                  : (sw + (size_t)o * (INF * 8) + (k8 - INF));
    float4 v0 = *(const float4*)src;
    float4 v1 = *(const float4*)(src + 4);
    f16x8 ov;
    ov[0] = (f16)v0.x; ov[1] = (f16)v0.y; ov[2] = (f16)v0.z; ov[3] = (f16)v0.w;
    ov[4] = (f16)v1.x; ov[5] = (f16)v1.y; ov[6] = (f16)v1.z; ov[7] = (f16)v1.w;
    // fragment-order destination
    int tn = o >> 8, rp = o & 255;
    int wcn = rp >> 6, n = (rp >> 4) & 3, la = rp & 15;
    int kt = r >> 3, c = r & 7, s = c >> 2, lb = c & 3;
    size_t off = (size_t)(tn * NKT + kt) * 16384 + wcn * 4096
               + (s * 4 + n) * 512 + (lb * 16 + la) * 8;
    *(f16x8*)(Wc + off) = ov;
    return;
  }

  int q = (blk - CONV_BLOCKS) * 256 + threadIdx.x;   // one thread per 4 (b,i)
  int b = q >> 8;
  int i0 = (q & 255) << 2;
  float4 xv = *(const float4*)(x + ((size_t)b << 10) + i0);
  float xa[4] = {xv.x, xv.y, xv.z, xv.w};

  float g[12];
#pragma unroll
  for (int j = 0; j < 12; ++j) g[j] = grid[j];
  float H  = g[1] - g[0];
  float r1 = 1.0f / H;
  float r2 = 0.5f * r1;
  float r3 = (1.0f / 3.0f) * r1;

  f16 sil[4];
  f16x8 bas[4];
#pragma unroll
  for (int e = 0; e < 4; ++e) {
    float v = xa[e];
    sil[e] = (f16)(v / (1.0f + __expf(-v)));
    float xe = fminf(fmaxf(v, -0.99f), 0.99f);
    float Bv[11];
#pragma unroll
    for (int j = 0; j < 11; ++j) Bv[j] = (xe >= g[j] && xe < g[j + 1]) ? 1.0f : 0.0f;
#pragma unroll
    for (int j = 0; j < 10; ++j) Bv[j] = (xe - g[j]) * r1 * Bv[j] + (g[j + 2] - xe) * r1 * Bv[j + 1];
#pragma unroll
    for (int j = 0; j < 9; ++j)  Bv[j] = (xe - g[j]) * r2 * Bv[j] + (g[j + 3] - xe) * r2 * Bv[j + 1];
#pragma unroll
    for (int j = 0; j < 8; ++j)  Bv[j] = (xe - g[j]) * r3 * Bv[j] + (g[j + 4] - xe) * r3 * Bv[j + 1];
#pragma unroll
    for (int n = 0; n < 8; ++n) bas[e][n] = (f16)Bv[n];
  }
  f16* row = Abuf + (size_t)b * KTOT;
  *(uint64_t*)(row + i0) = *(const uint64_t*)sil;
  f16* bp = row + INF + (size_t)i0 * 8;
#pragma unroll
  for (int e = 0; e < 4; ++e) *(f16x8*)(bp + e * 8) = bas[e];
}

// ---------------------------------------------------------------------------
// GEMM: C[8192,1024] = A[8192,9216] * W[1024,9216]^T   (split-K = 2)
// 128x256 tile, BK=64, 4 waves (1M x 4N), 16x16x32 MFMA, 2 blocks/CU.
// A via LDS (16 KB single buffer, proven swizzle); B via REGISTERS from the
// fragment-order Wc layout (coalesced dwordx4, double-buffered, unroll-2).
// Removes B's LDS write+read: LDS traffic/tile-pair 292->160 KB ~= MFMA time.
// Ledger per tile: vmcnt(0) | SBAR | {B(t+1) prefetch; 16 A-reads weave 32
// MFMA} | lgkm0 | SBAR | stage A(t+1) | 32 reg-only MFMA.
// ---------------------------------------------------------------------------
#define LDA(base, m, s) (*(const f16x8*)((base) + (((m)*16 + la) * 64 + ((((s)*4 + lb) ^ lasw) * 8))))

#define MFMA1(m, n, s, BF) acc[m][n] = __builtin_amdgcn_mfma_f32_16x16x32_f16(af[m][s], BF[(s)*4+(n)], acc[m][n], 0, 0, 0)
#define MFMA_S0(m0, BF) do { \
  MFMA1(m0,0,0,BF);   MFMA1(m0,1,0,BF);   MFMA1(m0,2,0,BF);   MFMA1(m0,3,0,BF); \
  MFMA1(m0+1,0,0,BF); MFMA1(m0+1,1,0,BF); MFMA1(m0+1,2,0,BF); MFMA1(m0+1,3,0,BF); } while (0)
#define MFMA_S1(m0, BF) do { \
  MFMA1(m0,0,1,BF);   MFMA1(m0,1,1,BF);   MFMA1(m0,2,1,BF);   MFMA1(m0,3,1,BF); \
  MFMA1(m0+1,0,1,BF); MFMA1(m0+1,1,1,BF); MFMA1(m0+1,2,1,BF); MFMA1(m0+1,3,1,BF); } while (0)

#define SCHED0 __builtin_amdgcn_sched_barrier(0)
#define SBARF  do { SCHED0; __builtin_amdgcn_s_barrier(); SCHED0; } while (0)
#define LGKM0  do { asm volatile("s_waitcnt lgkmcnt(0)" ::: "memory"); SCHED0; } while (0)

// one K-tile: compute with bfC, prefetch B(t+1) into bfN
#define TILE_BODY(bfC, bfN, t) do { \
  asm volatile("s_waitcnt vmcnt(0)" ::: "memory"); \
  SBARF; \
  if ((t) < NT - 1) { \
    const f16* bp_ = bSrc + (size_t)(ktbase + (t) + 1) * 16384; \
    bfN[0] = *(const f16x8*)(bp_);          bfN[1] = *(const f16x8*)(bp_ + 512); \
    bfN[2] = *(const f16x8*)(bp_ + 1024);   bfN[3] = *(const f16x8*)(bp_ + 1536); \
    bfN[4] = *(const f16x8*)(bp_ + 2048);   bfN[5] = *(const f16x8*)(bp_ + 2560); \
    bfN[6] = *(const f16x8*)(bp_ + 3072);   bfN[7] = *(const f16x8*)(bp_ + 3584); \
  } \
  af[0][0] = LDA(lsA, 0, 0); af[0][1] = LDA(lsA, 0, 1); \
  af[1][0] = LDA(lsA, 1, 0); af[1][1] = LDA(lsA, 1, 1); \
  __builtin_amdgcn_s_setprio(1); \
  af[2][0] = LDA(lsA, 2, 0); af[3][0] = LDA(lsA, 3, 0); \
  MFMA_S0(0, bfC); \
  af[2][1] = LDA(lsA, 2, 1); af[3][1] = LDA(lsA, 3, 1); \
  MFMA_S1(0, bfC); \
  af[4][0] = LDA(lsA, 4, 0); af[5][0] = LDA(lsA, 5, 0); \
  af[4][1] = LDA(lsA, 4, 1); af[5][1] = LDA(lsA, 5, 1); \
  MFMA_S0(2, bfC); \
  af[6][0] = LDA(lsA, 6, 0); af[7][0] = LDA(lsA, 7, 0); \
  af[6][1] = LDA(lsA, 6, 1); af[7][1] = LDA(lsA, 7, 1); \
  MFMA_S1(2, bfC); \
  __builtin_amdgcn_s_setprio(0); \
  LGKM0; \
  SBARF; \
  if ((t) < NT - 1) stageA((t) + 1); \
  __builtin_amdgcn_s_setprio(1); \
  MFMA_S0(4, bfC); MFMA_S1(4, bfC); \
  MFMA_S0(6, bfC); MFMA_S1(6, bfC); \
  __builtin_amdgcn_s_setprio(0); \
} while (0)

template <bool ATOMIC>
__global__ __launch_bounds__(256, 2) void kan_gemm_kernel(
    const f16* __restrict__ A, const f16* __restrict__ Wc,
    float* __restrict__ C, float* __restrict__ P1)
{
  __shared__ __align__(16) f16 lsA[128 * 64];   // 16 KB (A only, single buffer)

  const size_t K = KTOT;
  // L2-locality swizzle: the 8 wgs sharing an A-panel (same tm,split) land
  // on ONE XCD (FETCH 304->147MB, R7/R12).
  int bid = blockIdx.x;                    // 0..511
  int xcd = bid & 7;
  int u   = bid >> 3;                      // 0..63 within XCD
  int tm  = xcd * 8 + (u & 7);             // 64 M-tiles of 128 rows
  int tn  = (u >> 3) & 3;
  int split = u >> 5;
  int ktbase = split * NT;
  size_t kbase = (size_t)ktbase * 64;

  int tid = threadIdx.x;
  int w = tid >> 6, l = tid & 63;          // 4 waves
  int la = l & 15, lb = l >> 4, lasw = la & 7;

  // A staging (pre-swizzled source chunk; linear LDS dest) — proven
  int rh = tid >> 3;                       // row-in-line (0..31)
  int sc = (tid & 7) ^ (rh & 7);
  const f16* aSrc0 = A + (size_t)(tm * 128 + rh) * K + kbase + sc * 8;

  auto stageA = [&](int t) {               // A tile 16 KB = 4 lines
    size_t koff = (size_t)t * 64;
#pragma unroll
    for (int ln = 0; ln < 4; ++ln)
      gload16(aSrc0 + (size_t)ln * 32 * K + koff, lsA + ln * 2048 + w * 512);
  };

  // B fragment base: coalesced per-lane address in fragment-order Wc
  const f16* bSrc = Wc + (size_t)tn * NKT * 16384 + w * 4096 + l * 8;

  f16x8 af[8][2], bfX[8], bfY[8];
  f32x4 acc[8][4] = {};

  // ---- prologue: B(0) -> bfX, stage A(0)
  {
    const f16* bp_ = bSrc + (size_t)ktbase * 16384;
#pragma unroll
    for (int f = 0; f < 8; ++f) bfX[f] = *(const f16x8*)(bp_ + f * 512);
  }
  stageA(0);

  for (int t = 0; t < NT; t += 2) {
    TILE_BODY(bfX, bfY, t);
    TILE_BODY(bfY, bfX, t + 1);
  }

  // ---- epilogue ----
  int rowBase = tm * 128 + lb * 4;
  int colBase = tn * 256 + w * 64 + la;
  float* dst = ATOMIC ? C : (split ? P1 : C);
#pragma unroll
  for (int m = 0; m < 8; ++m)
#pragma unroll
    for (int n = 0; n < 4; ++n) {
      int col = colBase + n * 16;
#pragma unroll
      for (int j = 0; j < 4; ++j) {
        int row = rowBase + m * 16 + j;
        if (ATOMIC) atomicAdd(&C[(size_t)row * OUTF + col], acc[m][n][j]);
        else        dst[(size_t)row * OUTF + col] = acc[m][n][j];
      }
    }
}

// ---------------------------------------------------------------------------
__global__ __launch_bounds__(256) void reduce_kernel(
    float* __restrict__ out, const float* __restrict__ p)
{
  size_t i = ((size_t)blockIdx.x * 256 + threadIdx.x) * 4;
  f32x4 a = *(f32x4*)(out + i);
  f32x4 b = *(const f32x4*)(p + i);
  a += b;
  *(f32x4*)(out + i) = a;
}

// ---------------------------------------------------------------------------
extern "C" void kernel_launch(void* const* d_in, const int* in_sizes, int n_in,
                              void* d_out, int out_size, void* d_ws, size_t ws_size,
                              hipStream_t stream)
{
  const float* x  = (const float*)d_in[0];
  const float* bw = (const float*)d_in[1];
  const float* sw = (const float*)d_in[2];
  const float* gr = (const float*)d_in[3];
  float* out = (float*)d_out;

  f16* Wc = (f16*)d_ws;
  size_t wBytes = (size_t)OUTF * KTOT * sizeof(f16);      // 18.9 MB
  f16* Abuf = (f16*)((char*)d_ws + wBytes);               // 151 MB
  size_t aBytes = (size_t)BATCH * KTOT * sizeof(f16);
  size_t oBytes = (size_t)BATCH * OUTF * sizeof(float);   // 33.5 MB

  int prepBlocks = (BATCH * INF / 4) / 256;               // 8192
  fused_prep_kernel<<<CONV_BLOCKS + prepBlocks, 256, 0, stream>>>(
      bw, sw, x, gr, Wc, Abuf);

  if (ws_size >= wBytes + aBytes + oBytes) {
    float* P1 = (float*)((char*)d_ws + wBytes + aBytes);
    kan_gemm_kernel<false><<<512, 256, 0, stream>>>(Abuf, Wc, out, P1);
    reduce_kernel<<<(int)(oBytes / sizeof(float) / 4 / 256), 256, 0, stream>>>(out, P1);
  } else {
    hipMemsetAsync(d_out, 0, oBytes, stream);
    kan_gemm_kernel<true><<<512, 256, 0, stream>>>(Abuf, Wc, out, nullptr);
  }
}